// Round 4
// baseline (666.108 us; speedup 1.0000x reference)
//
#include <hip/hip_runtime.h>
#include <hip/hip_bf16.h>

#define LOG2E 1.4426950408889634f

typedef short bf16x8 __attribute__((ext_vector_type(8)));
typedef float f32x4  __attribute__((ext_vector_type(4)));

// ---------------- workspace layout ----------------
// float region (offsets in floats from d_ws)
#define OFF_BPf  16
#define OFF_SRWf (OFF_BPf + 384)
#define OFF_SRBf (OFF_SRWf + 1536)
#define OFF_GAf  (OFF_SRBf + 384)
#define OFF_BEf  (OFF_GAf + 384)
#define OFF_MUf  (OFF_BEf + 384)
#define OFF_VAf  (OFF_MUf + 384)     // ends at float 3856 = short 7712
// bf16 region (offsets in ushorts from d_ws)
#define U_XB 7712
#define U_WQ (U_XB + 6291456)
#define U_WK (U_WQ + 147456)
#define U_WV (U_WK + 147456)
#define U_WP (U_WV + 147456)
#define U_XK (U_WP + 147456)
#define U_QB (U_XK + 1572864)
#define U_KB (U_QB + 6291456)
#define U_VT (U_KB + 1572864)   // V transposed: [b*8+h][48][1024]
#define U_OB (U_VT + 1572864)   // attention output [b,n,384]
// total = 24,337,952 ushorts ~= 48.7 MB

static __device__ __forceinline__ float bfu(unsigned short u){ return __uint_as_float(((unsigned)u) << 16); }
static __device__ __forceinline__ float bf_lo(unsigned v){ return __uint_as_float(v << 16); }
static __device__ __forceinline__ float bf_hi(unsigned v){ return __uint_as_float(v & 0xFFFF0000u); }
static __device__ __forceinline__ unsigned short f2bf(float f){
  unsigned u = __float_as_uint(f);
  u += 0x7FFFu + ((u >> 16) & 1u);      // RNE
  return (unsigned short)(u >> 16);
}
static __device__ __forceinline__ unsigned pk2bf(float a, float b){
  return (unsigned)f2bf(a) | ((unsigned)f2bf(b) << 16);
}

// ---------------- dtype detection (bf16-packed vs fp32 inputs) ----------------
__global__ void detect_bf16(const unsigned* __restrict__ xraw, int* __restrict__ flag){
  unsigned w = xraw[threadIdx.x];
  unsigned e = (w >> 7) & 0xFFu;        // exponent of the LOW half if bf16-packed
  unsigned long long m = __ballot(e >= 118u && e <= 137u);
  if (threadIdx.x == 0) *flag = (__popcll(m) >= 40) ? 1 : 0;
}

// ---------------- canonicalize inputs (vectorized x8) ----------------
static __device__ __forceinline__ void cp8_bf(unsigned short* dst, const void* src, int off, bool bf){
  if (bf) { *(uint4*)dst = *(const uint4*)((const unsigned short*)src + off); }
  else {
    const float* s = (const float*)src + off;
    float4 a = *(const float4*)s, b = *(const float4*)(s + 4);
    uint4 o; o.x = pk2bf(a.x, a.y); o.y = pk2bf(a.z, a.w);
    o.z = pk2bf(b.x, b.y); o.w = pk2bf(b.z, b.w);
    *(uint4*)dst = o;
  }
}
static __device__ __forceinline__ void cp8_f(float* dst, const void* src, int off, bool bf){
  if (bf) {
    const unsigned short* s = (const unsigned short*)src + off;
    uint4 w = *(const uint4*)s;
    float4 a, b;
    a.x = bf_lo(w.x); a.y = bf_hi(w.x); a.z = bf_lo(w.y); a.w = bf_hi(w.y);
    b.x = bf_lo(w.z); b.y = bf_hi(w.z); b.z = bf_lo(w.w); b.w = bf_hi(w.w);
    *(float4*)dst = a; *(float4*)(dst + 4) = b;
  } else {
    const float* s = (const float*)src + off;
    *(float4*)dst = *(const float4*)s;
    *(float4*)(dst + 4) = *(const float4*)(s + 4);
  }
}

__global__ __launch_bounds__(256) void convert_all(
    const void* x, const void* wq, const void* wk, const void* wv, const void* wp,
    const void* bp, const void* srw, const void* srb, const void* ga, const void* be,
    const void* mu, const void* va, float* ws){
  const bool bf = ((const int*)ws)[0] != 0;
  unsigned short* u = (unsigned short*)ws;
  int g = blockIdx.x * 256 + threadIdx.x;     // group of 8 elements
  if (g < 786432) { cp8_bf(u + U_XB + g*8, x,  g*8, bf); return; }  g -= 786432;
  if (g < 18432)  { cp8_bf(u + U_WQ + g*8, wq, g*8, bf); return; }  g -= 18432;
  if (g < 18432)  { cp8_bf(u + U_WK + g*8, wk, g*8, bf); return; }  g -= 18432;
  if (g < 18432)  { cp8_bf(u + U_WV + g*8, wv, g*8, bf); return; }  g -= 18432;
  if (g < 18432)  { cp8_bf(u + U_WP + g*8, wp, g*8, bf); return; }  g -= 18432;
  if (g < 192)    { cp8_f(ws + OFF_SRWf + g*8, srw, g*8, bf); return; } g -= 192;
  if (g < 48)     { cp8_f(ws + OFF_BPf  + g*8, bp,  g*8, bf); return; } g -= 48;
  if (g < 48)     { cp8_f(ws + OFF_SRBf + g*8, srb, g*8, bf); return; } g -= 48;
  if (g < 48)     { cp8_f(ws + OFF_GAf  + g*8, ga,  g*8, bf); return; } g -= 48;
  if (g < 48)     { cp8_f(ws + OFF_BEf  + g*8, be,  g*8, bf); return; } g -= 48;
  if (g < 48)     { cp8_f(ws + OFF_MUf  + g*8, mu,  g*8, bf); return; } g -= 48;
  if (g < 48)     { cp8_f(ws + OFF_VAf  + g*8, va,  g*8, bf); }
}

// ---------------- depthwise conv 2x2 s2 + BN(eval) -> xk bf16 [B,1024,384] ----------------
__global__ __launch_bounds__(256) void sr_bn(const unsigned short* __restrict__ xb,
    const float* __restrict__ wsf, unsigned short* __restrict__ xkb){
  int idx = blockIdx.x * 256 + threadIdx.x;       // 1,572,864
  int c  = idx % 384;
  int nk = (idx / 384) & 1023;
  int b  = idx / (384 * 1024);
  int i = nk >> 5, j = nk & 31;
  const unsigned short* xp = xb + ((size_t)(b*4096 + i*128 + j*2))*384 + c;
  float acc = bfu(xp[0])      * wsf[OFF_SRWf + c*4 + 0]
            + bfu(xp[384])    * wsf[OFF_SRWf + c*4 + 1]
            + bfu(xp[64*384]) * wsf[OFF_SRWf + c*4 + 2]
            + bfu(xp[65*384]) * wsf[OFF_SRWf + c*4 + 3];
  float inv = rsqrtf(wsf[OFF_VAf + c] + 1e-5f) * wsf[OFF_GAf + c];
  float r = (acc + wsf[OFF_SRBf + c] - wsf[OFF_MUf + c]) * inv + wsf[OFF_BEf + c];
  xkb[idx] = f2bf(r);
}

// ---------------- merged Q/K/V projection (tight grid: y 0..127=Q, 128..159=K, 160..191=V) ----------------
__global__ __launch_bounds__(256) void proj_qkv(unsigned short* __restrict__ u){
  int z, by;
  if (blockIdx.y < 128)      { z = 0; by = blockIdx.y; }
  else if (blockIdx.y < 160) { z = 1; by = blockIdx.y - 128; }
  else                       { z = 2; by = blockIdx.y - 160; }
  const unsigned short* A = u + ((z == 0) ? U_XB : U_XK);
  const unsigned short* W = u + ((z == 0) ? U_WQ : (z == 1) ? U_WK : U_WV);

  __shared__ unsigned short As[128][40];
  __shared__ unsigned short Ws[128][40];
  const int tid = threadIdx.x;
  const int wave = tid >> 6, lane = tid & 63, lg = lane >> 4, ln = lane & 15;
  const int m0 = by * 128, n0 = blockIdx.x * 128;
  const int wm = (wave >> 1) * 64, wn = (wave & 1) * 64;
  f32x4 acc[4][4];
  #pragma unroll
  for (int i = 0; i < 4; ++i)
    #pragma unroll
    for (int j = 0; j < 4; ++j) acc[i][j] = (f32x4){0.f,0.f,0.f,0.f};

  const int arow = tid >> 1, acol = (tid & 1) * 16;
  for (int kt = 0; kt < 384; kt += 32) {
    uint4 a0 = *(const uint4*)&A[(size_t)(m0+arow)*384 + kt + acol];
    uint4 a1 = *(const uint4*)&A[(size_t)(m0+arow)*384 + kt + acol + 8];
    uint4 w0 = *(const uint4*)&W[(size_t)(n0+arow)*384 + kt + acol];
    uint4 w1 = *(const uint4*)&W[(size_t)(n0+arow)*384 + kt + acol + 8];
    __syncthreads();
    *(uint4*)&As[arow][acol] = a0;  *(uint4*)&As[arow][acol+8] = a1;
    *(uint4*)&Ws[arow][acol] = w0;  *(uint4*)&Ws[arow][acol+8] = w1;
    __syncthreads();
    bf16x8 af[4], wf[4];
    #pragma unroll
    for (int mi = 0; mi < 4; ++mi) af[mi] = *(const bf16x8*)&As[wm + mi*16 + ln][lg*8];
    #pragma unroll
    for (int ni = 0; ni < 4; ++ni) wf[ni] = *(const bf16x8*)&Ws[wn + ni*16 + ln][lg*8];
    #pragma unroll
    for (int mi = 0; mi < 4; ++mi)
      #pragma unroll
      for (int ni = 0; ni < 4; ++ni)
        acc[mi][ni] = __builtin_amdgcn_mfma_f32_16x16x32_bf16(af[mi], wf[ni], acc[mi][ni], 0, 0, 0);
  }

  unsigned short* outQ = u + U_QB;
  unsigned short* outK = u + U_KB;
  unsigned short* outV = u + U_VT;
  #pragma unroll
  for (int mi = 0; mi < 4; ++mi)
    #pragma unroll
    for (int ni = 0; ni < 4; ++ni)
      #pragma unroll
      for (int r = 0; r < 4; ++r) {
        int grow = m0 + wm + mi*16 + lg*4 + r;
        int gcol = n0 + wn + ni*16 + ln;
        unsigned short v = f2bf(acc[mi][ni][r]);
        if (z == 0)      outQ[(size_t)grow*384 + gcol] = v;
        else if (z == 1) outK[(size_t)grow*384 + gcol] = v;
        else {
          int hh = gcol / 48, d = gcol - hh*48;
          int bb = grow >> 10, mk = grow & 1023;
          outV[((size_t)((bb*8 + hh)*48 + d))*1024 + mk] = v;
        }
      }
}

// ---------------- out-projection GEMM + bias, dual-dtype store ----------------
__global__ __launch_bounds__(256) void gemm_out(const unsigned short* __restrict__ A,
    const unsigned short* __restrict__ W, const float* __restrict__ bias,
    void* __restrict__ out, const int* __restrict__ flag){
  __shared__ unsigned short As[128][40];
  __shared__ unsigned short Ws[128][40];
  const int tid = threadIdx.x;
  const int wave = tid >> 6, lane = tid & 63, lg = lane >> 4, ln = lane & 15;
  const int m0 = blockIdx.y * 128, n0 = blockIdx.x * 128;
  const int wm = (wave >> 1) * 64, wn = (wave & 1) * 64;
  f32x4 acc[4][4];
  #pragma unroll
  for (int i = 0; i < 4; ++i)
    #pragma unroll
    for (int j = 0; j < 4; ++j) acc[i][j] = (f32x4){0.f,0.f,0.f,0.f};

  const int arow = tid >> 1, acol = (tid & 1) * 16;
  for (int kt = 0; kt < 384; kt += 32) {
    uint4 a0 = *(const uint4*)&A[(size_t)(m0+arow)*384 + kt + acol];
    uint4 a1 = *(const uint4*)&A[(size_t)(m0+arow)*384 + kt + acol + 8];
    uint4 w0 = *(const uint4*)&W[(size_t)(n0+arow)*384 + kt + acol];
    uint4 w1 = *(const uint4*)&W[(size_t)(n0+arow)*384 + kt + acol + 8];
    __syncthreads();
    *(uint4*)&As[arow][acol] = a0;  *(uint4*)&As[arow][acol+8] = a1;
    *(uint4*)&Ws[arow][acol] = w0;  *(uint4*)&Ws[arow][acol+8] = w1;
    __syncthreads();
    bf16x8 af[4], wf[4];
    #pragma unroll
    for (int mi = 0; mi < 4; ++mi) af[mi] = *(const bf16x8*)&As[wm + mi*16 + ln][lg*8];
    #pragma unroll
    for (int ni = 0; ni < 4; ++ni) wf[ni] = *(const bf16x8*)&Ws[wn + ni*16 + ln][lg*8];
    #pragma unroll
    for (int mi = 0; mi < 4; ++mi)
      #pragma unroll
      for (int ni = 0; ni < 4; ++ni)
        acc[mi][ni] = __builtin_amdgcn_mfma_f32_16x16x32_bf16(af[mi], wf[ni], acc[mi][ni], 0, 0, 0);
  }

  const bool bff = (*flag != 0);
  #pragma unroll
  for (int mi = 0; mi < 4; ++mi)
    #pragma unroll
    for (int ni = 0; ni < 4; ++ni)
      #pragma unroll
      for (int r = 0; r < 4; ++r) {
        int grow = m0 + wm + mi*16 + lg*4 + r;
        int gcol = n0 + wn + ni*16 + ln;
        float v = acc[mi][ni][r] + bias[gcol];
        if (bff) ((unsigned short*)out)[(size_t)grow*384 + gcol] = f2bf(v);
        else     ((float*)out)[(size_t)grow*384 + gcol] = v;
      }
}

// ---------------- software-pipelined, barrier-free MFMA flash attention ----------------
// grid (64, 8, 4) = (q-tile 64, head, batch); 256 thr = 4 waves x 16 q-rows.
// S^T = K Q^T (no-max softmax: scores O(1), exp2 safe). Double-buffered K/rel
// register prefetch + early V issue hide global latency; P through wave-private
// LDS (no __syncthreads anywhere). l = fp32 running sum per lane, reduced at end.
struct KF { bf16x8 a0[4]; bf16x8 a1[4]; };
struct RF { uint2 rb[4]; float4 rf[4]; };

static __device__ __forceinline__ void loadK(KF& k, const unsigned short* __restrict__ kb,
    size_t kbase, int t, int lg, int ln){
  #pragma unroll
  for (int mt = 0; mt < 4; ++mt) {
    const unsigned short* kp = kb + kbase + ((size_t)(t*64 + mt*16 + ln))*384;
    k.a0[mt] = *(const bf16x8*)(kp + lg*8);
    bf16x8 z = {0,0,0,0,0,0,0,0};
    if (lg < 2) z = *(const bf16x8*)(kp + 32 + lg*8);
    k.a1[mt] = z;
  }
}
static __device__ __forceinline__ void loadRel(RF& r, const unsigned short* __restrict__ relh,
    const float* __restrict__ relf, bool bfm, size_t rbase, int t, int lg){
  size_t o0 = rbase + (size_t)t*64 + lg*4;
  if (bfm) {
    #pragma unroll
    for (int mt = 0; mt < 4; ++mt) r.rb[mt] = *(const uint2*)(relh + o0 + mt*16);
  } else {
    #pragma unroll
    for (int mt = 0; mt < 4; ++mt) r.rf[mt] = *(const float4*)(relf + o0 + mt*16);
  }
}
static __device__ __forceinline__ void loadV(bf16x8 vf[6], const unsigned short* __restrict__ vt,
    size_t vbase, int t, int lg, int ln){
  #pragma unroll
  for (int ks = 0; ks < 2; ++ks)
    #pragma unroll
    for (int nd = 0; nd < 3; ++nd)
      vf[ks*3+nd] = *(const bf16x8*)(vt + vbase + ((size_t)(nd*16 + ln))*1024 + t*64 + ks*32 + lg*8);
}

static __device__ __forceinline__ void attn_body(const KF& kf, const RF& rf, const bf16x8 vf[6],
    bool bfm, const bf16x8 qf0, const bf16x8 qf1, f32x4 o[3], float& lsum,
    unsigned short* __restrict__ PsW, int lg, int ln){
  const float SCL = 0.14433756729740643f * LOG2E;
  f32x4 s[4];
  #pragma unroll
  for (int mt = 0; mt < 4; ++mt) {
    s[mt] = __builtin_amdgcn_mfma_f32_16x16x32_bf16(kf.a0[mt], qf0, (f32x4){0.f,0.f,0.f,0.f}, 0, 0, 0);
    s[mt] = __builtin_amdgcn_mfma_f32_16x16x32_bf16(kf.a1[mt], qf1, s[mt], 0, 0, 0);
  }
  #pragma unroll
  for (int mt = 0; mt < 4; ++mt) {
    float r0, r1, r2, r3;
    if (bfm) {
      uint2 rr = rf.rb[mt];
      r0 = bf_lo(rr.x); r1 = bf_hi(rr.x); r2 = bf_lo(rr.y); r3 = bf_hi(rr.y);
    } else {
      float4 q = rf.rf[mt]; r0 = q.x; r1 = q.y; r2 = q.z; r3 = q.w;
    }
    float p0 = exp2f(fmaf(s[mt][0], SCL, r0 * LOG2E));
    float p1 = exp2f(fmaf(s[mt][1], SCL, r1 * LOG2E));
    float p2 = exp2f(fmaf(s[mt][2], SCL, r2 * LOG2E));
    float p3 = exp2f(fmaf(s[mt][3], SCL, r3 * LOG2E));
    lsum += (p0 + p1) + (p2 + p3);
    uint2 w; w.x = pk2bf(p0, p1); w.y = pk2bf(p2, p3);
    *(uint2*)(PsW + ln*72 + mt*16 + lg*4) = w;
  }
  #pragma unroll
  for (int ks = 0; ks < 2; ++ks) {
    bf16x8 pa = *(const bf16x8*)(PsW + ln*72 + ks*32 + lg*8);
    #pragma unroll
    for (int nd = 0; nd < 3; ++nd)
      o[nd] = __builtin_amdgcn_mfma_f32_16x16x32_bf16(pa, vf[ks*3+nd], o[nd], 0, 0, 0);
  }
}

__global__ __launch_bounds__(256, 3) void attn_mfma(const unsigned short* __restrict__ qb,
    const unsigned short* __restrict__ kb, const unsigned short* __restrict__ vt,
    const void* __restrict__ rel, const int* __restrict__ flag,
    unsigned short* __restrict__ ob){
  __shared__ unsigned short Ps[4][16][72];   // wave-private [q-row][k-col] bf16
  __shared__ float Ls[4][16];
  const int nb = blockIdx.x, h = blockIdx.y, b = blockIdx.z;
  const int n0 = nb * 64;
  const int tid = threadIdx.x, wave = tid >> 6, lane = tid & 63;
  const int lg = lane >> 4, ln = lane & 15;
  const int qrow0 = n0 + wave * 16;
  const bool bfm = (*flag != 0);
  unsigned short* PsW = &Ps[wave][0][0];

  // Q fragments (B-operand: lane = q-row, regs = head-dim; pad 48->64 with 0)
  const unsigned short* qp = qb + ((size_t)(b*4096 + qrow0 + ln))*384 + h*48;
  bf16x8 qf0 = *(const bf16x8*)(qp + lg*8);
  bf16x8 qf1 = {0,0,0,0,0,0,0,0};
  if (lg < 2) qf1 = *(const bf16x8*)(qp + 32 + lg*8);

  f32x4 o[3];
  o[0] = (f32x4){0.f,0.f,0.f,0.f}; o[1] = o[0]; o[2] = o[0];
  float lsum = 0.f;

  const float* relf = (const float*)rel;
  const unsigned short* relh = (const unsigned short*)rel;
  const size_t rbase = ((size_t)(h*4096 + qrow0 + ln)) * 1024;
  const size_t kbase = (size_t)(b*1024) * 384 + h*48;
  const size_t vbase = ((size_t)(b*8 + h)) * 48 * 1024;

  KF kA, kB; RF rA, rB; bf16x8 vA[6], vB[6];
  loadK(kA, kb, kbase, 0, lg, ln);
  loadRel(rA, relh, relf, bfm, rbase, 0, lg);

  #pragma unroll 1
  for (int it = 0; it < 8; ++it) {
    const int t0 = it*2, t1 = t0 + 1;
    const int t2 = (t1 + 1 < 16) ? t1 + 1 : 15;     // clamp: avoid OOB prefetch
    loadK(kB, kb, kbase, t1, lg, ln);
    loadRel(rB, relh, relf, bfm, rbase, t1, lg);
    loadV(vA, vt, vbase, t0, lg, ln);
    attn_body(kA, rA, vA, bfm, qf0, qf1, o, lsum, PsW, lg, ln);
    loadK(kA, kb, kbase, t2, lg, ln);
    loadRel(rA, relh, relf, bfm, rbase, t2, lg);
    loadV(vB, vt, vbase, t1, lg, ln);
    attn_body(kB, rB, vB, bfm, qf0, qf1, o, lsum, PsW, lg, ln);
  }

  // l: reduce over the 4 lanes sharing a q-row (lg groups), bounce via LDS to D-layout
  lsum += __shfl_xor(lsum, 16, 64);
  lsum += __shfl_xor(lsum, 32, 64);
  if (lg == 0) Ls[wave][ln] = lsum;
  float4 l4 = *(const float4*)&Ls[wave][lg*4];
  float linv[4] = {1.f/l4.x, 1.f/l4.y, 1.f/l4.z, 1.f/l4.w};

  #pragma unroll
  for (int r = 0; r < 4; ++r) {
    size_t rowb = ((size_t)(b*4096 + qrow0 + lg*4 + r))*384 + h*48 + ln;
    #pragma unroll
    for (int nd = 0; nd < 3; ++nd)
      ob[rowb + nd*16] = f2bf(o[nd][r] * linv[r]);
  }
}

extern "C" void kernel_launch(void* const* d_in, const int* in_sizes, int n_in,
                              void* d_out, int out_size, void* d_ws, size_t ws_size,
                              hipStream_t stream) {
  // d_in: 0=x 1=relative_pos 2=H 3=W 4=Wq 5=Wk 6=Wv 7=Wp 8=bp 9=sr_w 10=sr_b
  //       11=bn_gamma 12=bn_beta 13=bn_mean 14=bn_var
  float* ws = (float*)d_ws;
  int* flag = (int*)d_ws;
  unsigned short* u = (unsigned short*)d_ws;

  detect_bf16<<<1, 64, 0, stream>>>((const unsigned*)d_in[0], flag);
  convert_all<<<3363, 256, 0, stream>>>(d_in[0], d_in[4], d_in[5], d_in[6], d_in[7],
      d_in[8], d_in[9], d_in[10], d_in[11], d_in[12], d_in[13], d_in[14], ws);
  sr_bn<<<6144, 256, 0, stream>>>(u + U_XB, ws, u + U_XK);
  proj_qkv<<<dim3(3, 192), 256, 0, stream>>>(u);
  attn_mfma<<<dim3(64, 8, 4), 256, 0, stream>>>(u + U_QB, u + U_KB, u + U_VT, d_in[1], flag, u + U_OB);
  gemm_out<<<dim3(3, 128), 256, 0, stream>>>(u + U_OB, u + U_WP, ws + OFF_BPf, d_out, flag);
}

// Round 5
// 508.272 us; speedup vs baseline: 1.3105x; 1.3105x over previous
//
#include <hip/hip_runtime.h>
#include <hip/hip_bf16.h>

#define LOG2E 1.4426950408889634f

typedef short bf16x8 __attribute__((ext_vector_type(8)));
typedef float f32x4  __attribute__((ext_vector_type(4)));

// ---------------- workspace layout ----------------
// float region (offsets in floats from d_ws)
#define OFF_BPf  16
#define OFF_SRWf (OFF_BPf + 384)
#define OFF_SRBf (OFF_SRWf + 1536)
#define OFF_GAf  (OFF_SRBf + 384)
#define OFF_BEf  (OFF_GAf + 384)
#define OFF_MUf  (OFF_BEf + 384)
#define OFF_VAf  (OFF_MUf + 384)     // ends at float 3856 = short 7712
// bf16 region (offsets in ushorts from d_ws)
#define U_XB 7712
#define U_WQ (U_XB + 6291456)
#define U_WK (U_WQ + 147456)
#define U_WV (U_WK + 147456)
#define U_WP (U_WV + 147456)
#define U_XK (U_WP + 147456)
#define U_QB (U_XK + 1572864)
#define U_KB (U_QB + 6291456)
#define U_VT (U_KB + 1572864)   // V transposed: [b*8+h][48][1024]
#define U_OB (U_VT + 1572864)   // attention output [b,n,384]
// total = 24,337,952 ushorts ~= 48.7 MB

static __device__ __forceinline__ float bfu(unsigned short u){ return __uint_as_float(((unsigned)u) << 16); }
static __device__ __forceinline__ float bf_lo(unsigned v){ return __uint_as_float(v << 16); }
static __device__ __forceinline__ float bf_hi(unsigned v){ return __uint_as_float(v & 0xFFFF0000u); }
static __device__ __forceinline__ unsigned short f2bf(float f){
  unsigned u = __float_as_uint(f);
  u += 0x7FFFu + ((u >> 16) & 1u);      // RNE
  return (unsigned short)(u >> 16);
}
static __device__ __forceinline__ unsigned pk2bf(float a, float b){
  return (unsigned)f2bf(a) | ((unsigned)f2bf(b) << 16);
}

// ---------------- dtype detection (bf16-packed vs fp32 inputs) ----------------
__global__ void detect_bf16(const unsigned* __restrict__ xraw, int* __restrict__ flag){
  unsigned w = xraw[threadIdx.x];
  unsigned e = (w >> 7) & 0xFFu;        // exponent of the LOW half if bf16-packed
  unsigned long long m = __ballot(e >= 118u && e <= 137u);
  if (threadIdx.x == 0) *flag = (__popcll(m) >= 40) ? 1 : 0;
}

// ---------------- canonicalize inputs (vectorized x8) ----------------
static __device__ __forceinline__ void cp8_bf(unsigned short* dst, const void* src, int off, bool bf){
  if (bf) { *(uint4*)dst = *(const uint4*)((const unsigned short*)src + off); }
  else {
    const float* s = (const float*)src + off;
    float4 a = *(const float4*)s, b = *(const float4*)(s + 4);
    uint4 o; o.x = pk2bf(a.x, a.y); o.y = pk2bf(a.z, a.w);
    o.z = pk2bf(b.x, b.y); o.w = pk2bf(b.z, b.w);
    *(uint4*)dst = o;
  }
}
static __device__ __forceinline__ void cp8_f(float* dst, const void* src, int off, bool bf){
  if (bf) {
    const unsigned short* s = (const unsigned short*)src + off;
    uint4 w = *(const uint4*)s;
    float4 a, b;
    a.x = bf_lo(w.x); a.y = bf_hi(w.x); a.z = bf_lo(w.y); a.w = bf_hi(w.y);
    b.x = bf_lo(w.z); b.y = bf_hi(w.z); b.z = bf_lo(w.w); b.w = bf_hi(w.w);
    *(float4*)dst = a; *(float4*)(dst + 4) = b;
  } else {
    const float* s = (const float*)src + off;
    *(float4*)dst = *(const float4*)s;
    *(float4*)(dst + 4) = *(const float4*)(s + 4);
  }
}

__global__ __launch_bounds__(256) void convert_all(
    const void* x, const void* wq, const void* wk, const void* wv, const void* wp,
    const void* bp, const void* srw, const void* srb, const void* ga, const void* be,
    const void* mu, const void* va, float* ws){
  const bool bf = ((const int*)ws)[0] != 0;
  unsigned short* u = (unsigned short*)ws;
  int g = blockIdx.x * 256 + threadIdx.x;     // group of 8 elements
  if (g < 786432) { cp8_bf(u + U_XB + g*8, x,  g*8, bf); return; }  g -= 786432;
  if (g < 18432)  { cp8_bf(u + U_WQ + g*8, wq, g*8, bf); return; }  g -= 18432;
  if (g < 18432)  { cp8_bf(u + U_WK + g*8, wk, g*8, bf); return; }  g -= 18432;
  if (g < 18432)  { cp8_bf(u + U_WV + g*8, wv, g*8, bf); return; }  g -= 18432;
  if (g < 18432)  { cp8_bf(u + U_WP + g*8, wp, g*8, bf); return; }  g -= 18432;
  if (g < 192)    { cp8_f(ws + OFF_SRWf + g*8, srw, g*8, bf); return; } g -= 192;
  if (g < 48)     { cp8_f(ws + OFF_BPf  + g*8, bp,  g*8, bf); return; } g -= 48;
  if (g < 48)     { cp8_f(ws + OFF_SRBf + g*8, srb, g*8, bf); return; } g -= 48;
  if (g < 48)     { cp8_f(ws + OFF_GAf  + g*8, ga,  g*8, bf); return; } g -= 48;
  if (g < 48)     { cp8_f(ws + OFF_BEf  + g*8, be,  g*8, bf); return; } g -= 48;
  if (g < 48)     { cp8_f(ws + OFF_MUf  + g*8, mu,  g*8, bf); return; } g -= 48;
  if (g < 48)     { cp8_f(ws + OFF_VAf  + g*8, va,  g*8, bf); }
}

// ---------------- depthwise conv 2x2 s2 + BN(eval) -> xk bf16 [B,1024,384] ----------------
__global__ __launch_bounds__(256) void sr_bn(const unsigned short* __restrict__ xb,
    const float* __restrict__ wsf, unsigned short* __restrict__ xkb){
  int idx = blockIdx.x * 256 + threadIdx.x;       // 1,572,864
  int c  = idx % 384;
  int nk = (idx / 384) & 1023;
  int b  = idx / (384 * 1024);
  int i = nk >> 5, j = nk & 31;
  const unsigned short* xp = xb + ((size_t)(b*4096 + i*128 + j*2))*384 + c;
  float acc = bfu(xp[0])      * wsf[OFF_SRWf + c*4 + 0]
            + bfu(xp[384])    * wsf[OFF_SRWf + c*4 + 1]
            + bfu(xp[64*384]) * wsf[OFF_SRWf + c*4 + 2]
            + bfu(xp[65*384]) * wsf[OFF_SRWf + c*4 + 3];
  float inv = rsqrtf(wsf[OFF_VAf + c] + 1e-5f) * wsf[OFF_GAf + c];
  float r = (acc + wsf[OFF_SRBf + c] - wsf[OFF_MUf + c]) * inv + wsf[OFF_BEf + c];
  xkb[idx] = f2bf(r);
}

// ---------------- merged Q/K/V projection (tight grid: y 0..127=Q, 128..159=K, 160..191=V) ----------------
__global__ __launch_bounds__(256) void proj_qkv(unsigned short* __restrict__ u){
  int z, by;
  if (blockIdx.y < 128)      { z = 0; by = blockIdx.y; }
  else if (blockIdx.y < 160) { z = 1; by = blockIdx.y - 128; }
  else                       { z = 2; by = blockIdx.y - 160; }
  const unsigned short* A = u + ((z == 0) ? U_XB : U_XK);
  const unsigned short* W = u + ((z == 0) ? U_WQ : (z == 1) ? U_WK : U_WV);

  __shared__ unsigned short As[128][40];
  __shared__ unsigned short Ws[128][40];
  const int tid = threadIdx.x;
  const int wave = tid >> 6, lane = tid & 63, lg = lane >> 4, ln = lane & 15;
  const int m0 = by * 128, n0 = blockIdx.x * 128;
  const int wm = (wave >> 1) * 64, wn = (wave & 1) * 64;
  f32x4 acc[4][4];
  #pragma unroll
  for (int i = 0; i < 4; ++i)
    #pragma unroll
    for (int j = 0; j < 4; ++j) acc[i][j] = (f32x4){0.f,0.f,0.f,0.f};

  const int arow = tid >> 1, acol = (tid & 1) * 16;
  for (int kt = 0; kt < 384; kt += 32) {
    uint4 a0 = *(const uint4*)&A[(size_t)(m0+arow)*384 + kt + acol];
    uint4 a1 = *(const uint4*)&A[(size_t)(m0+arow)*384 + kt + acol + 8];
    uint4 w0 = *(const uint4*)&W[(size_t)(n0+arow)*384 + kt + acol];
    uint4 w1 = *(const uint4*)&W[(size_t)(n0+arow)*384 + kt + acol + 8];
    __syncthreads();
    *(uint4*)&As[arow][acol] = a0;  *(uint4*)&As[arow][acol+8] = a1;
    *(uint4*)&Ws[arow][acol] = w0;  *(uint4*)&Ws[arow][acol+8] = w1;
    __syncthreads();
    bf16x8 af[4], wf[4];
    #pragma unroll
    for (int mi = 0; mi < 4; ++mi) af[mi] = *(const bf16x8*)&As[wm + mi*16 + ln][lg*8];
    #pragma unroll
    for (int ni = 0; ni < 4; ++ni) wf[ni] = *(const bf16x8*)&Ws[wn + ni*16 + ln][lg*8];
    #pragma unroll
    for (int mi = 0; mi < 4; ++mi)
      #pragma unroll
      for (int ni = 0; ni < 4; ++ni)
        acc[mi][ni] = __builtin_amdgcn_mfma_f32_16x16x32_bf16(af[mi], wf[ni], acc[mi][ni], 0, 0, 0);
  }

  unsigned short* outQ = u + U_QB;
  unsigned short* outK = u + U_KB;
  unsigned short* outV = u + U_VT;
  #pragma unroll
  for (int mi = 0; mi < 4; ++mi)
    #pragma unroll
    for (int ni = 0; ni < 4; ++ni)
      #pragma unroll
      for (int r = 0; r < 4; ++r) {
        int grow = m0 + wm + mi*16 + lg*4 + r;
        int gcol = n0 + wn + ni*16 + ln;
        unsigned short v = f2bf(acc[mi][ni][r]);
        if (z == 0)      outQ[(size_t)grow*384 + gcol] = v;
        else if (z == 1) outK[(size_t)grow*384 + gcol] = v;
        else {
          int hh = gcol / 48, d = gcol - hh*48;
          int bb = grow >> 10, mk = grow & 1023;
          outV[((size_t)((bb*8 + hh)*48 + d))*1024 + mk] = v;
        }
      }
}

// ---------------- out-projection GEMM + bias, dual-dtype store ----------------
__global__ __launch_bounds__(256) void gemm_out(const unsigned short* __restrict__ A,
    const unsigned short* __restrict__ W, const float* __restrict__ bias,
    void* __restrict__ out, const int* __restrict__ flag){
  __shared__ unsigned short As[128][40];
  __shared__ unsigned short Ws[128][40];
  const int tid = threadIdx.x;
  const int wave = tid >> 6, lane = tid & 63, lg = lane >> 4, ln = lane & 15;
  const int m0 = blockIdx.y * 128, n0 = blockIdx.x * 128;
  const int wm = (wave >> 1) * 64, wn = (wave & 1) * 64;
  f32x4 acc[4][4];
  #pragma unroll
  for (int i = 0; i < 4; ++i)
    #pragma unroll
    for (int j = 0; j < 4; ++j) acc[i][j] = (f32x4){0.f,0.f,0.f,0.f};

  const int arow = tid >> 1, acol = (tid & 1) * 16;
  for (int kt = 0; kt < 384; kt += 32) {
    uint4 a0 = *(const uint4*)&A[(size_t)(m0+arow)*384 + kt + acol];
    uint4 a1 = *(const uint4*)&A[(size_t)(m0+arow)*384 + kt + acol + 8];
    uint4 w0 = *(const uint4*)&W[(size_t)(n0+arow)*384 + kt + acol];
    uint4 w1 = *(const uint4*)&W[(size_t)(n0+arow)*384 + kt + acol + 8];
    __syncthreads();
    *(uint4*)&As[arow][acol] = a0;  *(uint4*)&As[arow][acol+8] = a1;
    *(uint4*)&Ws[arow][acol] = w0;  *(uint4*)&Ws[arow][acol+8] = w1;
    __syncthreads();
    bf16x8 af[4], wf[4];
    #pragma unroll
    for (int mi = 0; mi < 4; ++mi) af[mi] = *(const bf16x8*)&As[wm + mi*16 + ln][lg*8];
    #pragma unroll
    for (int ni = 0; ni < 4; ++ni) wf[ni] = *(const bf16x8*)&Ws[wn + ni*16 + ln][lg*8];
    #pragma unroll
    for (int mi = 0; mi < 4; ++mi)
      #pragma unroll
      for (int ni = 0; ni < 4; ++ni)
        acc[mi][ni] = __builtin_amdgcn_mfma_f32_16x16x32_bf16(af[mi], wf[ni], acc[mi][ni], 0, 0, 0);
  }

  const bool bff = (*flag != 0);
  #pragma unroll
  for (int mi = 0; mi < 4; ++mi)
    #pragma unroll
    for (int ni = 0; ni < 4; ++ni)
      #pragma unroll
      for (int r = 0; r < 4; ++r) {
        int grow = m0 + wm + mi*16 + lg*4 + r;
        int gcol = n0 + wn + ni*16 + ln;
        float v = acc[mi][ni][r] + bias[gcol];
        if (bff) ((unsigned short*)out)[(size_t)grow*384 + gcol] = f2bf(v);
        else     ((float*)out)[(size_t)grow*384 + gcol] = v;
      }
}

// ---------------- software-pipelined, barrier-free MFMA flash attention ----------------
// grid (256, 8) with XCD swizzle; 256 thr = 4 waves x 16 q-rows (q-tile 64).
// S^T = K Q^T (no-max softmax). FLAT register pipeline (no structs -> no scratch
// spill): K & rel double-buffered one tile ahead; V single-buffered, loaded
// before the S-MFMAs that precede its use. P via wave-private LDS; no barriers.

#define LOADK(K0, K1, T) do {                                                   \
  _Pragma("unroll")                                                             \
  for (int mt = 0; mt < 4; ++mt) {                                              \
    const unsigned short* kp_ = kb + kbase + ((size_t)((T)*64 + mt*16 + ln))*384;\
    K0[mt] = *(const bf16x8*)(kp_ + lg*8);                                      \
    bf16x8 z_ = {0,0,0,0,0,0,0,0};                                              \
    if (lg < 2) z_ = *(const bf16x8*)(kp_ + 32 + lg*8);                         \
    K1[mt] = z_;                                                                \
  } } while (0)

#define LOADREL(RR, T) do {                                                     \
  if (bfm) {                                                                    \
    _Pragma("unroll")                                                           \
    for (int mt = 0; mt < 4; ++mt)                                              \
      RR[mt] = *(const uint2*)(relh + rbase + (size_t)(T)*64 + mt*16 + lg*4);   \
  } else {                                                                      \
    _Pragma("unroll")                                                           \
    for (int mt = 0; mt < 4; ++mt) {                                            \
      float4 q_ = *(const float4*)(relf + rbase + (size_t)(T)*64 + mt*16 + lg*4);\
      RR[mt].x = pk2bf(q_.x, q_.y); RR[mt].y = pk2bf(q_.z, q_.w);               \
    }                                                                           \
  } } while (0)

#define LOADV(VV, T) do {                                                       \
  _Pragma("unroll")                                                             \
  for (int ks = 0; ks < 2; ++ks)                                                \
    _Pragma("unroll")                                                           \
    for (int nd = 0; nd < 3; ++nd)                                              \
      VV[ks*3+nd] = *(const bf16x8*)(vt + vbase + ((size_t)(nd*16 + ln))*1024   \
                                      + (T)*64 + ks*32 + lg*8);                 \
  } while (0)

#define ATTN_BODY(K0, K1, RR, VV) do {                                          \
  f32x4 s_[4];                                                                  \
  _Pragma("unroll")                                                             \
  for (int mt = 0; mt < 4; ++mt) {                                              \
    s_[mt] = __builtin_amdgcn_mfma_f32_16x16x32_bf16(K0[mt], qf0,               \
              (f32x4){0.f,0.f,0.f,0.f}, 0, 0, 0);                               \
    s_[mt] = __builtin_amdgcn_mfma_f32_16x16x32_bf16(K1[mt], qf1, s_[mt], 0,0,0);\
  }                                                                             \
  _Pragma("unroll")                                                             \
  for (int mt = 0; mt < 4; ++mt) {                                              \
    float r0_ = bf_lo(RR[mt].x), r1_ = bf_hi(RR[mt].x);                         \
    float r2_ = bf_lo(RR[mt].y), r3_ = bf_hi(RR[mt].y);                         \
    float p0_ = exp2f(fmaf(s_[mt][0], SCL, r0_ * LOG2E));                       \
    float p1_ = exp2f(fmaf(s_[mt][1], SCL, r1_ * LOG2E));                       \
    float p2_ = exp2f(fmaf(s_[mt][2], SCL, r2_ * LOG2E));                       \
    float p3_ = exp2f(fmaf(s_[mt][3], SCL, r3_ * LOG2E));                       \
    lsum += (p0_ + p1_) + (p2_ + p3_);                                          \
    uint2 w_; w_.x = pk2bf(p0_, p1_); w_.y = pk2bf(p2_, p3_);                   \
    *(uint2*)(PsW + ln*72 + mt*16 + lg*4) = w_;                                 \
  }                                                                             \
  _Pragma("unroll")                                                             \
  for (int ks = 0; ks < 2; ++ks) {                                              \
    bf16x8 pa_ = *(const bf16x8*)(PsW + ln*72 + ks*32 + lg*8);                  \
    _Pragma("unroll")                                                           \
    for (int nd = 0; nd < 3; ++nd)                                              \
      o[nd] = __builtin_amdgcn_mfma_f32_16x16x32_bf16(pa_, VV[ks*3+nd],         \
               o[nd], 0, 0, 0);                                                 \
  } } while (0)

__global__ __launch_bounds__(256, 3) void attn_mfma(const unsigned short* __restrict__ qb,
    const unsigned short* __restrict__ kb, const unsigned short* __restrict__ vt,
    const void* __restrict__ rel, const int* __restrict__ flag,
    unsigned short* __restrict__ ob){
  __shared__ unsigned short Ps[4][16][72];   // wave-private [q-row][k-col] bf16, 9216 B
  __shared__ float Ls[4][16];
  // XCD swizzle: the 4 batch-copies of each (nb,h) sit 8 apart in x -> same XCD.
  const int x = blockIdx.x;
  const int nb = (x >> 5) * 8 + (x & 7);
  const int b  = (x >> 3) & 3;
  const int h  = blockIdx.y;
  const int tid = threadIdx.x, wave = tid >> 6, lane = tid & 63;
  const int lg = lane >> 4, ln = lane & 15;
  const int qrow0 = nb * 64 + wave * 16;
  const bool bfm = (*flag != 0);
  unsigned short* PsW = &Ps[wave][0][0];
  const float SCL = 0.14433756729740643f * LOG2E;

  // Q fragments (B-operand: lane = q-row, regs = head-dim; pad 48->64 with 0)
  const unsigned short* qp = qb + ((size_t)(b*4096 + qrow0 + ln))*384 + h*48;
  bf16x8 qf0 = *(const bf16x8*)(qp + lg*8);
  bf16x8 qf1 = {0,0,0,0,0,0,0,0};
  if (lg < 2) qf1 = *(const bf16x8*)(qp + 32 + lg*8);

  f32x4 o[3];
  o[0] = (f32x4){0.f,0.f,0.f,0.f}; o[1] = o[0]; o[2] = o[0];
  float lsum = 0.f;

  const float* relf = (const float*)rel;
  const unsigned short* relh = (const unsigned short*)rel;
  const size_t rbase = ((size_t)(h*4096 + qrow0 + ln)) * 1024;
  const size_t kbase = (size_t)(b*1024) * 384 + h*48;
  const size_t vbase = ((size_t)(b*8 + h)) * 48 * 1024;

  bf16x8 kA0[4], kA1[4], kB0[4], kB1[4], vv[6];
  uint2 rA[4], rB[4];
  LOADK(kA0, kA1, 0);
  LOADREL(rA, 0);

  #pragma unroll 1
  for (int it = 0; it < 8; ++it) {
    const int t0 = it*2, t1 = t0 + 1;
    const int t2 = (t1 + 1 < 16) ? t1 + 1 : 15;     // clamped prefetch
    LOADK(kB0, kB1, t1);
    LOADREL(rB, t1);
    LOADV(vv, t0);
    ATTN_BODY(kA0, kA1, rA, vv);
    LOADK(kA0, kA1, t2);
    LOADREL(rA, t2);
    LOADV(vv, t1);
    ATTN_BODY(kB0, kB1, rB, vv);
  }

  // l: reduce across the 4 lg-lanes of each q-row, transpose via wave-private LDS
  lsum += __shfl_xor(lsum, 16, 64);
  lsum += __shfl_xor(lsum, 32, 64);
  if (lg == 0) Ls[wave][ln] = lsum;
  float4 l4 = *(const float4*)&Ls[wave][lg*4];
  float linv[4] = {1.f/l4.x, 1.f/l4.y, 1.f/l4.z, 1.f/l4.w};

  #pragma unroll
  for (int r = 0; r < 4; ++r) {
    size_t rowb = ((size_t)(b*4096 + qrow0 + lg*4 + r))*384 + h*48 + ln;
    #pragma unroll
    for (int nd = 0; nd < 3; ++nd)
      ob[rowb + nd*16] = f2bf(o[nd][r] * linv[r]);
  }
}

extern "C" void kernel_launch(void* const* d_in, const int* in_sizes, int n_in,
                              void* d_out, int out_size, void* d_ws, size_t ws_size,
                              hipStream_t stream) {
  // d_in: 0=x 1=relative_pos 2=H 3=W 4=Wq 5=Wk 6=Wv 7=Wp 8=bp 9=sr_w 10=sr_b
  //       11=bn_gamma 12=bn_beta 13=bn_mean 14=bn_var
  float* ws = (float*)d_ws;
  int* flag = (int*)d_ws;
  unsigned short* u = (unsigned short*)d_ws;

  detect_bf16<<<1, 64, 0, stream>>>((const unsigned*)d_in[0], flag);
  convert_all<<<3363, 256, 0, stream>>>(d_in[0], d_in[4], d_in[5], d_in[6], d_in[7],
      d_in[8], d_in[9], d_in[10], d_in[11], d_in[12], d_in[13], d_in[14], ws);
  sr_bn<<<6144, 256, 0, stream>>>(u + U_XB, ws, u + U_XK);
  proj_qkv<<<dim3(3, 192), 256, 0, stream>>>(u);
  attn_mfma<<<dim3(256, 8), 256, 0, stream>>>(u + U_QB, u + U_KB, u + U_VT, d_in[1], flag, u + U_OB);
  gemm_out<<<dim3(3, 128), 256, 0, stream>>>(u + U_OB, u + U_WP, ws + OFF_BPf, d_out, flag);
}

// Round 6
// 427.801 us; speedup vs baseline: 1.5571x; 1.1881x over previous
//
#include <hip/hip_runtime.h>
#include <hip/hip_bf16.h>

#define LOG2E 1.4426950408889634f

typedef short bf16x8 __attribute__((ext_vector_type(8)));
typedef float f32x4  __attribute__((ext_vector_type(4)));

// ---------------- workspace layout ----------------
// float region (offsets in floats from d_ws)
#define OFF_BPf  16
#define OFF_SRWf (OFF_BPf + 384)
#define OFF_SRBf (OFF_SRWf + 1536)
#define OFF_GAf  (OFF_SRBf + 384)
#define OFF_BEf  (OFF_GAf + 384)
#define OFF_MUf  (OFF_BEf + 384)
#define OFF_VAf  (OFF_MUf + 384)     // ends at float 3856 = short 7712
// bf16 region (offsets in ushorts from d_ws)
#define U_XB 7712
#define U_WQ (U_XB + 6291456)
#define U_WK (U_WQ + 147456)
#define U_WV (U_WK + 147456)
#define U_WP (U_WV + 147456)
#define U_XK (U_WP + 147456)
#define U_QB (U_XK + 1572864)
#define U_KB (U_QB + 6291456)
#define U_VT (U_KB + 1572864)   // V transposed: [b*8+h][48][1024]
#define U_OB (U_VT + 1572864)   // attention output [b,n,384]
// total = 24,337,952 ushorts ~= 48.7 MB

static __device__ __forceinline__ float bfu(unsigned short u){ return __uint_as_float(((unsigned)u) << 16); }
static __device__ __forceinline__ float bf_lo(unsigned v){ return __uint_as_float(v << 16); }
static __device__ __forceinline__ float bf_hi(unsigned v){ return __uint_as_float(v & 0xFFFF0000u); }
static __device__ __forceinline__ unsigned short f2bf(float f){
  unsigned u = __float_as_uint(f);
  u += 0x7FFFu + ((u >> 16) & 1u);      // RNE
  return (unsigned short)(u >> 16);
}
static __device__ __forceinline__ unsigned pk2bf(float a, float b){
  return (unsigned)f2bf(a) | ((unsigned)f2bf(b) << 16);
}

// ---------------- dtype detection (bf16-packed vs fp32 inputs) ----------------
__global__ void detect_bf16(const unsigned* __restrict__ xraw, int* __restrict__ flag){
  unsigned w = xraw[threadIdx.x];
  unsigned e = (w >> 7) & 0xFFu;        // exponent of the LOW half if bf16-packed
  unsigned long long m = __ballot(e >= 118u && e <= 137u);
  if (threadIdx.x == 0) *flag = (__popcll(m) >= 40) ? 1 : 0;
}

// ---------------- canonicalize inputs (vectorized x8) ----------------
static __device__ __forceinline__ void cp8_bf(unsigned short* dst, const void* src, int off, bool bf){
  if (bf) { *(uint4*)dst = *(const uint4*)((const unsigned short*)src + off); }
  else {
    const float* s = (const float*)src + off;
    float4 a = *(const float4*)s, b = *(const float4*)(s + 4);
    uint4 o; o.x = pk2bf(a.x, a.y); o.y = pk2bf(a.z, a.w);
    o.z = pk2bf(b.x, b.y); o.w = pk2bf(b.z, b.w);
    *(uint4*)dst = o;
  }
}
static __device__ __forceinline__ void cp8_f(float* dst, const void* src, int off, bool bf){
  if (bf) {
    const unsigned short* s = (const unsigned short*)src + off;
    uint4 w = *(const uint4*)s;
    float4 a, b;
    a.x = bf_lo(w.x); a.y = bf_hi(w.x); a.z = bf_lo(w.y); a.w = bf_hi(w.y);
    b.x = bf_lo(w.z); b.y = bf_hi(w.z); b.z = bf_lo(w.w); b.w = bf_hi(w.w);
    *(float4*)dst = a; *(float4*)(dst + 4) = b;
  } else {
    const float* s = (const float*)src + off;
    *(float4*)dst = *(const float4*)s;
    *(float4*)(dst + 4) = *(const float4*)(s + 4);
  }
}

__global__ __launch_bounds__(256) void convert_all(
    const void* x, const void* wq, const void* wk, const void* wv, const void* wp,
    const void* bp, const void* srw, const void* srb, const void* ga, const void* be,
    const void* mu, const void* va, float* ws){
  const bool bf = ((const int*)ws)[0] != 0;
  unsigned short* u = (unsigned short*)ws;
  int g = blockIdx.x * 256 + threadIdx.x;     // group of 8 elements
  if (g < 786432) { cp8_bf(u + U_XB + g*8, x,  g*8, bf); return; }  g -= 786432;
  if (g < 18432)  { cp8_bf(u + U_WQ + g*8, wq, g*8, bf); return; }  g -= 18432;
  if (g < 18432)  { cp8_bf(u + U_WK + g*8, wk, g*8, bf); return; }  g -= 18432;
  if (g < 18432)  { cp8_bf(u + U_WV + g*8, wv, g*8, bf); return; }  g -= 18432;
  if (g < 18432)  { cp8_bf(u + U_WP + g*8, wp, g*8, bf); return; }  g -= 18432;
  if (g < 192)    { cp8_f(ws + OFF_SRWf + g*8, srw, g*8, bf); return; } g -= 192;
  if (g < 48)     { cp8_f(ws + OFF_BPf  + g*8, bp,  g*8, bf); return; } g -= 48;
  if (g < 48)     { cp8_f(ws + OFF_SRBf + g*8, srb, g*8, bf); return; } g -= 48;
  if (g < 48)     { cp8_f(ws + OFF_GAf  + g*8, ga,  g*8, bf); return; } g -= 48;
  if (g < 48)     { cp8_f(ws + OFF_BEf  + g*8, be,  g*8, bf); return; } g -= 48;
  if (g < 48)     { cp8_f(ws + OFF_MUf  + g*8, mu,  g*8, bf); return; } g -= 48;
  if (g < 48)     { cp8_f(ws + OFF_VAf  + g*8, va,  g*8, bf); }
}

// ---------------- depthwise conv 2x2 s2 + BN(eval) -> xk bf16 [B,1024,384] ----------------
__global__ __launch_bounds__(256) void sr_bn(const unsigned short* __restrict__ xb,
    const float* __restrict__ wsf, unsigned short* __restrict__ xkb){
  int idx = blockIdx.x * 256 + threadIdx.x;       // 1,572,864
  int c  = idx % 384;
  int nk = (idx / 384) & 1023;
  int b  = idx / (384 * 1024);
  int i = nk >> 5, j = nk & 31;
  const unsigned short* xp = xb + ((size_t)(b*4096 + i*128 + j*2))*384 + c;
  float acc = bfu(xp[0])      * wsf[OFF_SRWf + c*4 + 0]
            + bfu(xp[384])    * wsf[OFF_SRWf + c*4 + 1]
            + bfu(xp[64*384]) * wsf[OFF_SRWf + c*4 + 2]
            + bfu(xp[65*384]) * wsf[OFF_SRWf + c*4 + 3];
  float inv = rsqrtf(wsf[OFF_VAf + c] + 1e-5f) * wsf[OFF_GAf + c];
  float r = (acc + wsf[OFF_SRBf + c] - wsf[OFF_MUf + c]) * inv + wsf[OFF_BEf + c];
  xkb[idx] = f2bf(r);
}

// ---------------- merged Q/K/V projection (tight grid: y 0..127=Q, 128..159=K, 160..191=V) ----------------
__global__ __launch_bounds__(256) void proj_qkv(unsigned short* __restrict__ u){
  int z, by;
  if (blockIdx.y < 128)      { z = 0; by = blockIdx.y; }
  else if (blockIdx.y < 160) { z = 1; by = blockIdx.y - 128; }
  else                       { z = 2; by = blockIdx.y - 160; }
  const unsigned short* A = u + ((z == 0) ? U_XB : U_XK);
  const unsigned short* W = u + ((z == 0) ? U_WQ : (z == 1) ? U_WK : U_WV);

  __shared__ unsigned short As[128][40];
  __shared__ unsigned short Ws[128][40];
  const int tid = threadIdx.x;
  const int wave = tid >> 6, lane = tid & 63, lg = lane >> 4, ln = lane & 15;
  const int m0 = by * 128, n0 = blockIdx.x * 128;
  const int wm = (wave >> 1) * 64, wn = (wave & 1) * 64;
  f32x4 acc[4][4];
  #pragma unroll
  for (int i = 0; i < 4; ++i)
    #pragma unroll
    for (int j = 0; j < 4; ++j) acc[i][j] = (f32x4){0.f,0.f,0.f,0.f};

  const int arow = tid >> 1, acol = (tid & 1) * 16;
  for (int kt = 0; kt < 384; kt += 32) {
    uint4 a0 = *(const uint4*)&A[(size_t)(m0+arow)*384 + kt + acol];
    uint4 a1 = *(const uint4*)&A[(size_t)(m0+arow)*384 + kt + acol + 8];
    uint4 w0 = *(const uint4*)&W[(size_t)(n0+arow)*384 + kt + acol];
    uint4 w1 = *(const uint4*)&W[(size_t)(n0+arow)*384 + kt + acol + 8];
    __syncthreads();
    *(uint4*)&As[arow][acol] = a0;  *(uint4*)&As[arow][acol+8] = a1;
    *(uint4*)&Ws[arow][acol] = w0;  *(uint4*)&Ws[arow][acol+8] = w1;
    __syncthreads();
    bf16x8 af[4], wf[4];
    #pragma unroll
    for (int mi = 0; mi < 4; ++mi) af[mi] = *(const bf16x8*)&As[wm + mi*16 + ln][lg*8];
    #pragma unroll
    for (int ni = 0; ni < 4; ++ni) wf[ni] = *(const bf16x8*)&Ws[wn + ni*16 + ln][lg*8];
    #pragma unroll
    for (int mi = 0; mi < 4; ++mi)
      #pragma unroll
      for (int ni = 0; ni < 4; ++ni)
        acc[mi][ni] = __builtin_amdgcn_mfma_f32_16x16x32_bf16(af[mi], wf[ni], acc[mi][ni], 0, 0, 0);
  }

  unsigned short* outQ = u + U_QB;
  unsigned short* outK = u + U_KB;
  unsigned short* outV = u + U_VT;
  #pragma unroll
  for (int mi = 0; mi < 4; ++mi)
    #pragma unroll
    for (int ni = 0; ni < 4; ++ni)
      #pragma unroll
      for (int r = 0; r < 4; ++r) {
        int grow = m0 + wm + mi*16 + lg*4 + r;
        int gcol = n0 + wn + ni*16 + ln;
        unsigned short v = f2bf(acc[mi][ni][r]);
        if (z == 0)      outQ[(size_t)grow*384 + gcol] = v;
        else if (z == 1) outK[(size_t)grow*384 + gcol] = v;
        else {
          int hh = gcol / 48, d = gcol - hh*48;
          int bb = grow >> 10, mk = grow & 1023;
          outV[((size_t)((bb*8 + hh)*48 + d))*1024 + mk] = v;
        }
      }
}

// ---------------- out-projection GEMM + bias, dual-dtype store ----------------
__global__ __launch_bounds__(256) void gemm_out(const unsigned short* __restrict__ A,
    const unsigned short* __restrict__ W, const float* __restrict__ bias,
    void* __restrict__ out, const int* __restrict__ flag){
  __shared__ unsigned short As[128][40];
  __shared__ unsigned short Ws[128][40];
  const int tid = threadIdx.x;
  const int wave = tid >> 6, lane = tid & 63, lg = lane >> 4, ln = lane & 15;
  const int m0 = blockIdx.y * 128, n0 = blockIdx.x * 128;
  const int wm = (wave >> 1) * 64, wn = (wave & 1) * 64;
  f32x4 acc[4][4];
  #pragma unroll
  for (int i = 0; i < 4; ++i)
    #pragma unroll
    for (int j = 0; j < 4; ++j) acc[i][j] = (f32x4){0.f,0.f,0.f,0.f};

  const int arow = tid >> 1, acol = (tid & 1) * 16;
  for (int kt = 0; kt < 384; kt += 32) {
    uint4 a0 = *(const uint4*)&A[(size_t)(m0+arow)*384 + kt + acol];
    uint4 a1 = *(const uint4*)&A[(size_t)(m0+arow)*384 + kt + acol + 8];
    uint4 w0 = *(const uint4*)&W[(size_t)(n0+arow)*384 + kt + acol];
    uint4 w1 = *(const uint4*)&W[(size_t)(n0+arow)*384 + kt + acol + 8];
    __syncthreads();
    *(uint4*)&As[arow][acol] = a0;  *(uint4*)&As[arow][acol+8] = a1;
    *(uint4*)&Ws[arow][acol] = w0;  *(uint4*)&Ws[arow][acol+8] = w1;
    __syncthreads();
    bf16x8 af[4], wf[4];
    #pragma unroll
    for (int mi = 0; mi < 4; ++mi) af[mi] = *(const bf16x8*)&As[wm + mi*16 + ln][lg*8];
    #pragma unroll
    for (int ni = 0; ni < 4; ++ni) wf[ni] = *(const bf16x8*)&Ws[wn + ni*16 + ln][lg*8];
    #pragma unroll
    for (int mi = 0; mi < 4; ++mi)
      #pragma unroll
      for (int ni = 0; ni < 4; ++ni)
        acc[mi][ni] = __builtin_amdgcn_mfma_f32_16x16x32_bf16(af[mi], wf[ni], acc[mi][ni], 0, 0, 0);
  }

  const bool bff = (*flag != 0);
  #pragma unroll
  for (int mi = 0; mi < 4; ++mi)
    #pragma unroll
    for (int ni = 0; ni < 4; ++ni)
      #pragma unroll
      for (int r = 0; r < 4; ++r) {
        int grow = m0 + wm + mi*16 + lg*4 + r;
        int gcol = n0 + wn + ni*16 + ln;
        float v = acc[mi][ni][r] + bias[gcol];
        if (bff) ((unsigned short*)out)[(size_t)grow*384 + gcol] = f2bf(v);
        else     ((float*)out)[(size_t)grow*384 + gcol] = v;
      }
}

// ---------------- MFMA flash attention: 32 q-rows/wave, interleaved loads ----------------
// grid (128, 8): b = x>>5, nb = x&31 -> the 4 batch copies of each (nb,h) share
// x mod 8 -> same XCD -> rel L2-shared. 256 thr = 4 waves, each owns 32 q-rows
// (2 q-frags). S^T = K Q^T; no-max softmax (scores O(1)); P via wave-private LDS
// (no barriers). Load placement: K at tile top; rel interleaved between S-MFMA
// groups (8 MFMAs of cover); V at PV-phase start (first PV mfma waits vf[0] only).
// K regs die after S-phase, keeping peak pressure ~125 under the 128 cap of
// __launch_bounds__(256,4) -> 4 blocks/CU resident, grid = exactly 1 generation.
__global__ __launch_bounds__(256, 4) void attn_mfma(const unsigned short* __restrict__ qb,
    const unsigned short* __restrict__ kb, const unsigned short* __restrict__ vt,
    const void* __restrict__ rel, const int* __restrict__ flag,
    unsigned short* __restrict__ ob){
  __shared__ unsigned short Ps[4][32][72];   // wave-private [q-row][k-col] bf16
  __shared__ float Ls[4][2][16];
  const int b = blockIdx.x >> 5, nb = blockIdx.x & 31, h = blockIdx.y;
  const int tid = threadIdx.x, wave = tid >> 6, lane = tid & 63;
  const int lg = lane >> 4, ln = lane & 15;
  const int qrow0 = nb * 128 + wave * 32;
  const bool bfm = (*flag != 0);
  unsigned short* PsW = &Ps[wave][0][0];
  const float SCL = 0.14433756729740643f * LOG2E;

  // Q fragments (B-operand: lane = q-row, regs = head-dim; pad 48->64 with 0)
  bf16x8 qf0[2], qf1[2];
  #pragma unroll
  for (int qt = 0; qt < 2; ++qt) {
    const unsigned short* qp = qb + ((size_t)(b*4096 + qrow0 + qt*16 + ln))*384 + h*48;
    qf0[qt] = *(const bf16x8*)(qp + lg*8);
    bf16x8 z = {0,0,0,0,0,0,0,0};
    if (lg < 2) z = *(const bf16x8*)(qp + 32 + lg*8);
    qf1[qt] = z;
  }

  f32x4 o[2][3];
  #pragma unroll
  for (int qt = 0; qt < 2; ++qt) { o[qt][0] = (f32x4){0.f,0.f,0.f,0.f}; o[qt][1] = o[qt][0]; o[qt][2] = o[qt][0]; }
  float lsum[2] = {0.f, 0.f};

  const float* relf = (const float*)rel;
  const unsigned short* relh = (const unsigned short*)rel;
  const size_t rbase = ((size_t)(h*4096 + qrow0 + ln)) * 1024;   // + qt*16*1024
  const size_t kbase = (size_t)(b*1024) * 384 + h*48;
  const size_t vbase = ((size_t)(b*8 + h)) * 48 * 1024;

  #pragma unroll 1
  for (int t = 0; t < 16; ++t) {
    // --- K loads (tile top; L2-resident: 96 KB/(b,h) reused by 32 blocks) ---
    bf16x8 kf0[4], kf1[4];
    #pragma unroll
    for (int mt = 0; mt < 4; ++mt) {
      const unsigned short* kp = kb + kbase + ((size_t)(t*64 + mt*16 + ln))*384;
      kf0[mt] = *(const bf16x8*)(kp + lg*8);
      bf16x8 z = {0,0,0,0,0,0,0,0};
      if (lg < 2) z = *(const bf16x8*)(kp + 32 + lg*8);
      kf1[mt] = z;
    }

    // --- S-phase: 16 MFMAs with rel loads interleaved between mt groups ---
    f32x4 s[4][2];
    uint2 rr[2][4];
    #pragma unroll
    for (int mt = 0; mt < 4; ++mt) {
      #pragma unroll
      for (int qt = 0; qt < 2; ++qt) {
        s[mt][qt] = __builtin_amdgcn_mfma_f32_16x16x32_bf16(kf0[mt], qf0[qt], (f32x4){0.f,0.f,0.f,0.f}, 0, 0, 0);
        s[mt][qt] = __builtin_amdgcn_mfma_f32_16x16x32_bf16(kf1[mt], qf1[qt], s[mt][qt], 0, 0, 0);
      }
      // rel loads for this mt (consumed next phase -> latency covered by MFMAs)
      #pragma unroll
      for (int qt = 0; qt < 2; ++qt) {
        size_t off = rbase + (size_t)qt*16384 + (size_t)t*64 + mt*16 + lg*4;
        if (bfm) rr[qt][mt] = *(const uint2*)(relh + off);
        else {
          float4 q_ = *(const float4*)(relf + off);
          rr[qt][mt].x = pk2bf(q_.x, q_.y); rr[qt][mt].y = pk2bf(q_.z, q_.w);
        }
      }
    }

    // --- softmax numerator: p = exp2(s*scale*log2e + rel*log2e), P -> LDS ---
    #pragma unroll
    for (int qt = 0; qt < 2; ++qt) {
      float lacc = 0.f;
      #pragma unroll
      for (int mt = 0; mt < 4; ++mt) {
        float r0 = bf_lo(rr[qt][mt].x), r1 = bf_hi(rr[qt][mt].x);
        float r2 = bf_lo(rr[qt][mt].y), r3 = bf_hi(rr[qt][mt].y);
        float p0 = exp2f(fmaf(s[mt][qt][0], SCL, r0 * LOG2E));
        float p1 = exp2f(fmaf(s[mt][qt][1], SCL, r1 * LOG2E));
        float p2 = exp2f(fmaf(s[mt][qt][2], SCL, r2 * LOG2E));
        float p3 = exp2f(fmaf(s[mt][qt][3], SCL, r3 * LOG2E));
        lacc += (p0 + p1) + (p2 + p3);
        uint2 w; w.x = pk2bf(p0, p1); w.y = pk2bf(p2, p3);
        *(uint2*)(PsW + (qt*16 + ln)*72 + mt*16 + lg*4) = w;
      }
      lsum[qt] += lacc;
    }

    // --- PV-phase: V loads first (L2-resident), then 12 MFMAs from LDS P ---
    bf16x8 vf[6];
    #pragma unroll
    for (int ks = 0; ks < 2; ++ks)
      #pragma unroll
      for (int nd = 0; nd < 3; ++nd)
        vf[ks*3+nd] = *(const bf16x8*)(vt + vbase + ((size_t)(nd*16 + ln))*1024 + t*64 + ks*32 + lg*8);
    #pragma unroll
    for (int ks = 0; ks < 2; ++ks)
      #pragma unroll
      for (int qt = 0; qt < 2; ++qt) {
        bf16x8 pa = *(const bf16x8*)(PsW + (qt*16 + ln)*72 + ks*32 + lg*8);
        #pragma unroll
        for (int nd = 0; nd < 3; ++nd)
          o[qt][nd] = __builtin_amdgcn_mfma_f32_16x16x32_bf16(pa, vf[ks*3+nd], o[qt][nd], 0, 0, 0);
      }
  }

  // l: reduce across the 4 lg-lanes of each q-row, transpose via wave-private LDS
  #pragma unroll
  for (int qt = 0; qt < 2; ++qt) {
    lsum[qt] += __shfl_xor(lsum[qt], 16, 64);
    lsum[qt] += __shfl_xor(lsum[qt], 32, 64);
    if (lg == 0) Ls[wave][qt][ln] = lsum[qt];
  }
  #pragma unroll
  for (int qt = 0; qt < 2; ++qt) {
    float4 l4 = *(const float4*)&Ls[wave][qt][lg*4];
    float linv[4] = {1.f/l4.x, 1.f/l4.y, 1.f/l4.z, 1.f/l4.w};
    #pragma unroll
    for (int r = 0; r < 4; ++r) {
      size_t rowb = ((size_t)(b*4096 + qrow0 + qt*16 + lg*4 + r))*384 + h*48 + ln;
      #pragma unroll
      for (int nd = 0; nd < 3; ++nd)
        ob[rowb + nd*16] = f2bf(o[qt][nd][r] * linv[r]);
    }
  }
}

extern "C" void kernel_launch(void* const* d_in, const int* in_sizes, int n_in,
                              void* d_out, int out_size, void* d_ws, size_t ws_size,
                              hipStream_t stream) {
  // d_in: 0=x 1=relative_pos 2=H 3=W 4=Wq 5=Wk 6=Wv 7=Wp 8=bp 9=sr_w 10=sr_b
  //       11=bn_gamma 12=bn_beta 13=bn_mean 14=bn_var
  float* ws = (float*)d_ws;
  int* flag = (int*)d_ws;
  unsigned short* u = (unsigned short*)d_ws;

  detect_bf16<<<1, 64, 0, stream>>>((const unsigned*)d_in[0], flag);
  convert_all<<<3363, 256, 0, stream>>>(d_in[0], d_in[4], d_in[5], d_in[6], d_in[7],
      d_in[8], d_in[9], d_in[10], d_in[11], d_in[12], d_in[13], d_in[14], ws);
  sr_bn<<<6144, 256, 0, stream>>>(u + U_XB, ws, u + U_XK);
  proj_qkv<<<dim3(3, 192), 256, 0, stream>>>(u);
  attn_mfma<<<dim3(128, 8), 256, 0, stream>>>(u + U_QB, u + U_KB, u + U_VT, d_in[1], flag, u + U_OB);
  gemm_out<<<dim3(3, 128), 256, 0, stream>>>(u + U_OB, u + U_WP, ws + OFF_BPf, d_out, flag);
}

// Round 7
// 358.838 us; speedup vs baseline: 1.8563x; 1.1922x over previous
//
#include <hip/hip_runtime.h>
#include <hip/hip_bf16.h>

#define LOG2E 1.4426950408889634f

typedef short bf16x8 __attribute__((ext_vector_type(8)));
typedef float f32x4  __attribute__((ext_vector_type(4)));

// ---------------- workspace layout ----------------
#define OFF_BPf  16
#define OFF_SRWf (OFF_BPf + 384)
#define OFF_SRBf (OFF_SRWf + 1536)
#define OFF_GAf  (OFF_SRBf + 384)
#define OFF_BEf  (OFF_GAf + 384)
#define OFF_MUf  (OFF_BEf + 384)
#define OFF_VAf  (OFF_MUf + 384)     // ends at float 3856 = short 7712
#define U_XB 7712
#define U_WQ (U_XB + 6291456)
#define U_WK (U_WQ + 147456)
#define U_WV (U_WK + 147456)
#define U_WP (U_WV + 147456)
#define U_XK (U_WP + 147456)
#define U_QB (U_XK + 1572864)
#define U_KB (U_QB + 6291456)
#define U_VT (U_KB + 1572864)   // V transposed: [b*8+h][48][1024]
#define U_OB (U_VT + 1572864)   // attention output [b,n,384]

static __device__ __forceinline__ float bfu(unsigned short u){ return __uint_as_float(((unsigned)u) << 16); }
static __device__ __forceinline__ float bf_lo(unsigned v){ return __uint_as_float(v << 16); }
static __device__ __forceinline__ float bf_hi(unsigned v){ return __uint_as_float(v & 0xFFFF0000u); }
static __device__ __forceinline__ unsigned short f2bf(float f){
  unsigned u = __float_as_uint(f);
  u += 0x7FFFu + ((u >> 16) & 1u);      // RNE
  return (unsigned short)(u >> 16);
}
static __device__ __forceinline__ unsigned pk2bf(float a, float b){
  return (unsigned)f2bf(a) | ((unsigned)f2bf(b) << 16);
}
// hardware packed fp32->bf16x2 (v_cvt_pk_bf16_f32, RNE)
static __device__ __forceinline__ unsigned pkcvt(float a, float b){
  float2 f; f.x = a; f.y = b;
  __hip_bfloat162 h = __float22bfloat162_rn(f);
  union { __hip_bfloat162 h2; unsigned u; } cv; cv.h2 = h; return cv.u;
}
// async global->LDS, 16 B per lane; LDS dest = wave-uniform base + lane*16
static __device__ __forceinline__ void gld_lds16(const void* g, void* l){
  __builtin_amdgcn_global_load_lds((const __attribute__((address_space(1))) void*)g,
                                   (__attribute__((address_space(3))) void*)l, 16, 0, 0);
}

// ---------------- dtype detection (bf16-packed vs fp32 inputs) ----------------
__global__ void detect_bf16(const unsigned* __restrict__ xraw, int* __restrict__ flag){
  unsigned w = xraw[threadIdx.x];
  unsigned e = (w >> 7) & 0xFFu;
  unsigned long long m = __ballot(e >= 118u && e <= 137u);
  if (threadIdx.x == 0) *flag = (__popcll(m) >= 40) ? 1 : 0;
}

// ---------------- canonicalize inputs (vectorized x8) ----------------
static __device__ __forceinline__ void cp8_bf(unsigned short* dst, const void* src, int off, bool bf){
  if (bf) { *(uint4*)dst = *(const uint4*)((const unsigned short*)src + off); }
  else {
    const float* s = (const float*)src + off;
    float4 a = *(const float4*)s, b = *(const float4*)(s + 4);
    uint4 o; o.x = pk2bf(a.x, a.y); o.y = pk2bf(a.z, a.w);
    o.z = pk2bf(b.x, b.y); o.w = pk2bf(b.z, b.w);
    *(uint4*)dst = o;
  }
}
static __device__ __forceinline__ void cp8_f(float* dst, const void* src, int off, bool bf){
  if (bf) {
    const unsigned short* s = (const unsigned short*)src + off;
    uint4 w = *(const uint4*)s;
    float4 a, b;
    a.x = bf_lo(w.x); a.y = bf_hi(w.x); a.z = bf_lo(w.y); a.w = bf_hi(w.y);
    b.x = bf_lo(w.z); b.y = bf_hi(w.z); b.z = bf_lo(w.w); b.w = bf_hi(w.w);
    *(float4*)dst = a; *(float4*)(dst + 4) = b;
  } else {
    const float* s = (const float*)src + off;
    *(float4*)dst = *(const float4*)s;
    *(float4*)(dst + 4) = *(const float4*)(s + 4);
  }
}

__global__ __launch_bounds__(256) void convert_all(
    const void* x, const void* wq, const void* wk, const void* wv, const void* wp,
    const void* bp, const void* srw, const void* srb, const void* ga, const void* be,
    const void* mu, const void* va, float* ws){
  const bool bf = ((const int*)ws)[0] != 0;
  unsigned short* u = (unsigned short*)ws;
  int g = blockIdx.x * 256 + threadIdx.x;
  if (g < 786432) { cp8_bf(u + U_XB + g*8, x,  g*8, bf); return; }  g -= 786432;
  if (g < 18432)  { cp8_bf(u + U_WQ + g*8, wq, g*8, bf); return; }  g -= 18432;
  if (g < 18432)  { cp8_bf(u + U_WK + g*8, wk, g*8, bf); return; }  g -= 18432;
  if (g < 18432)  { cp8_bf(u + U_WV + g*8, wv, g*8, bf); return; }  g -= 18432;
  if (g < 18432)  { cp8_bf(u + U_WP + g*8, wp, g*8, bf); return; }  g -= 18432;
  if (g < 192)    { cp8_f(ws + OFF_SRWf + g*8, srw, g*8, bf); return; } g -= 192;
  if (g < 48)     { cp8_f(ws + OFF_BPf  + g*8, bp,  g*8, bf); return; } g -= 48;
  if (g < 48)     { cp8_f(ws + OFF_SRBf + g*8, srb, g*8, bf); return; } g -= 48;
  if (g < 48)     { cp8_f(ws + OFF_GAf  + g*8, ga,  g*8, bf); return; } g -= 48;
  if (g < 48)     { cp8_f(ws + OFF_BEf  + g*8, be,  g*8, bf); return; } g -= 48;
  if (g < 48)     { cp8_f(ws + OFF_MUf  + g*8, mu,  g*8, bf); return; } g -= 48;
  if (g < 48)     { cp8_f(ws + OFF_VAf  + g*8, va,  g*8, bf); }
}

// ---------------- depthwise conv 2x2 s2 + BN(eval), vectorized x8 ----------------
__global__ __launch_bounds__(256) void sr_bn(const unsigned short* __restrict__ xb,
    const float* __restrict__ wsf, unsigned short* __restrict__ xkb){
  int idx = blockIdx.x * 256 + threadIdx.x;       // 196,608 = 4*1024*48
  int c8 = idx % 48;
  int nk = (idx / 48) & 1023;
  int b  = idx / (48 * 1024);
  int i = nk >> 5, j = nk & 31;
  int c0 = c8 * 8;
  const unsigned short* xp = xb + ((size_t)(b*4096 + i*128 + j*2))*384 + c0;
  unsigned aw[4], bw[4], cw[4], dw[4];
  *(uint4*)aw = *(const uint4*)(xp);
  *(uint4*)bw = *(const uint4*)(xp + 384);
  *(uint4*)cw = *(const uint4*)(xp + 64*384);
  *(uint4*)dw = *(const uint4*)(xp + 65*384);
  unsigned out[4];
  #pragma unroll
  for (int k2 = 0; k2 < 4; ++k2) {
    float r2[2];
    #pragma unroll
    for (int half = 0; half < 2; ++half) {
      int k = k2*2 + half;
      int c = c0 + k;
      float xa = half ? bf_hi(aw[k2]) : bf_lo(aw[k2]);
      float xbv = half ? bf_hi(bw[k2]) : bf_lo(bw[k2]);
      float xc = half ? bf_hi(cw[k2]) : bf_lo(cw[k2]);
      float xd = half ? bf_hi(dw[k2]) : bf_lo(dw[k2]);
      float acc = xa*wsf[OFF_SRWf+c*4] + xbv*wsf[OFF_SRWf+c*4+1]
                + xc*wsf[OFF_SRWf+c*4+2] + xd*wsf[OFF_SRWf+c*4+3];
      float inv = rsqrtf(wsf[OFF_VAf+c] + 1e-5f) * wsf[OFF_GAf+c];
      r2[half] = (acc + wsf[OFF_SRBf+c] - wsf[OFF_MUf+c]) * inv + wsf[OFF_BEf+c];
    }
    out[k2] = pkcvt(r2[0], r2[1]);
  }
  *(uint4*)(xkb + (size_t)idx*8) = *(uint4*)out;
}

// ---------------- merged Q/K/V projection ----------------
__global__ __launch_bounds__(256) void proj_qkv(unsigned short* __restrict__ u){
  int z, by;
  if (blockIdx.y < 128)      { z = 0; by = blockIdx.y; }
  else if (blockIdx.y < 160) { z = 1; by = blockIdx.y - 128; }
  else                       { z = 2; by = blockIdx.y - 160; }
  const unsigned short* A = u + ((z == 0) ? U_XB : U_XK);
  const unsigned short* W = u + ((z == 0) ? U_WQ : (z == 1) ? U_WK : U_WV);

  __shared__ unsigned short As[128][40];
  __shared__ unsigned short Ws[128][40];
  const int tid = threadIdx.x;
  const int wave = tid >> 6, lane = tid & 63, lg = lane >> 4, ln = lane & 15;
  const int m0 = by * 128, n0 = blockIdx.x * 128;
  const int wm = (wave >> 1) * 64, wn = (wave & 1) * 64;
  f32x4 acc[4][4];
  #pragma unroll
  for (int i = 0; i < 4; ++i)
    #pragma unroll
    for (int j = 0; j < 4; ++j) acc[i][j] = (f32x4){0.f,0.f,0.f,0.f};

  const int arow = tid >> 1, acol = (tid & 1) * 16;
  for (int kt = 0; kt < 384; kt += 32) {
    uint4 a0 = *(const uint4*)&A[(size_t)(m0+arow)*384 + kt + acol];
    uint4 a1 = *(const uint4*)&A[(size_t)(m0+arow)*384 + kt + acol + 8];
    uint4 w0 = *(const uint4*)&W[(size_t)(n0+arow)*384 + kt + acol];
    uint4 w1 = *(const uint4*)&W[(size_t)(n0+arow)*384 + kt + acol + 8];
    __syncthreads();
    *(uint4*)&As[arow][acol] = a0;  *(uint4*)&As[arow][acol+8] = a1;
    *(uint4*)&Ws[arow][acol] = w0;  *(uint4*)&Ws[arow][acol+8] = w1;
    __syncthreads();
    bf16x8 af[4], wf[4];
    #pragma unroll
    for (int mi = 0; mi < 4; ++mi) af[mi] = *(const bf16x8*)&As[wm + mi*16 + ln][lg*8];
    #pragma unroll
    for (int ni = 0; ni < 4; ++ni) wf[ni] = *(const bf16x8*)&Ws[wn + ni*16 + ln][lg*8];
    #pragma unroll
    for (int mi = 0; mi < 4; ++mi)
      #pragma unroll
      for (int ni = 0; ni < 4; ++ni)
        acc[mi][ni] = __builtin_amdgcn_mfma_f32_16x16x32_bf16(af[mi], wf[ni], acc[mi][ni], 0, 0, 0);
  }

  unsigned short* outQ = u + U_QB;
  unsigned short* outK = u + U_KB;
  unsigned short* outV = u + U_VT;
  #pragma unroll
  for (int mi = 0; mi < 4; ++mi)
    #pragma unroll
    for (int ni = 0; ni < 4; ++ni) {
      int gcol = n0 + wn + ni*16 + ln;
      if (z == 2) {
        // V^T packed store: rows r are m-consecutive -> one 8 B store of 4 bf16
        int grow0 = m0 + wm + mi*16 + lg*4;
        int hh = gcol / 48, d = gcol - hh*48;
        int bb = grow0 >> 10, mk = grow0 & 1023;
        uint2 st; st.x = pkcvt(acc[mi][ni][0], acc[mi][ni][1]);
        st.y = pkcvt(acc[mi][ni][2], acc[mi][ni][3]);
        *(uint2*)&outV[((size_t)((bb*8 + hh)*48 + d))*1024 + mk] = st;
      } else {
        unsigned short* dst = (z == 0) ? outQ : outK;
        #pragma unroll
        for (int r = 0; r < 4; ++r) {
          int grow = m0 + wm + mi*16 + lg*4 + r;
          dst[(size_t)grow*384 + gcol] = f2bf(acc[mi][ni][r]);
        }
      }
    }
}

// ---------------- out-projection GEMM + bias, dual-dtype store ----------------
__global__ __launch_bounds__(256) void gemm_out(const unsigned short* __restrict__ A,
    const unsigned short* __restrict__ W, const float* __restrict__ bias,
    void* __restrict__ out, const int* __restrict__ flag){
  __shared__ unsigned short As[128][40];
  __shared__ unsigned short Ws[128][40];
  const int tid = threadIdx.x;
  const int wave = tid >> 6, lane = tid & 63, lg = lane >> 4, ln = lane & 15;
  const int m0 = blockIdx.y * 128, n0 = blockIdx.x * 128;
  const int wm = (wave >> 1) * 64, wn = (wave & 1) * 64;
  f32x4 acc[4][4];
  #pragma unroll
  for (int i = 0; i < 4; ++i)
    #pragma unroll
    for (int j = 0; j < 4; ++j) acc[i][j] = (f32x4){0.f,0.f,0.f,0.f};

  const int arow = tid >> 1, acol = (tid & 1) * 16;
  for (int kt = 0; kt < 384; kt += 32) {
    uint4 a0 = *(const uint4*)&A[(size_t)(m0+arow)*384 + kt + acol];
    uint4 a1 = *(const uint4*)&A[(size_t)(m0+arow)*384 + kt + acol + 8];
    uint4 w0 = *(const uint4*)&W[(size_t)(n0+arow)*384 + kt + acol];
    uint4 w1 = *(const uint4*)&W[(size_t)(n0+arow)*384 + kt + acol + 8];
    __syncthreads();
    *(uint4*)&As[arow][acol] = a0;  *(uint4*)&As[arow][acol+8] = a1;
    *(uint4*)&Ws[arow][acol] = w0;  *(uint4*)&Ws[arow][acol+8] = w1;
    __syncthreads();
    bf16x8 af[4], wf[4];
    #pragma unroll
    for (int mi = 0; mi < 4; ++mi) af[mi] = *(const bf16x8*)&As[wm + mi*16 + ln][lg*8];
    #pragma unroll
    for (int ni = 0; ni < 4; ++ni) wf[ni] = *(const bf16x8*)&Ws[wn + ni*16 + ln][lg*8];
    #pragma unroll
    for (int mi = 0; mi < 4; ++mi)
      #pragma unroll
      for (int ni = 0; ni < 4; ++ni)
        acc[mi][ni] = __builtin_amdgcn_mfma_f32_16x16x32_bf16(af[mi], wf[ni], acc[mi][ni], 0, 0, 0);
  }

  const bool bff = (*flag != 0);
  #pragma unroll
  for (int mi = 0; mi < 4; ++mi)
    #pragma unroll
    for (int ni = 0; ni < 4; ++ni)
      #pragma unroll
      for (int r = 0; r < 4; ++r) {
        int grow = m0 + wm + mi*16 + lg*4 + r;
        int gcol = n0 + wn + ni*16 + ln;
        float v = acc[mi][ni][r] + bias[gcol];
        if (bff) ((unsigned short*)out)[(size_t)grow*384 + gcol] = f2bf(v);
        else     ((float*)out)[(size_t)grow*384 + gcol] = v;
      }
}

// ---------------- MFMA flash attention with async LDS staging (m97 pattern) ----------------
// grid (128, 8): b = x>>5, nb = x&31 (4 batch copies of (nb,h) share XCD).
// 256 thr = 4 waves x 32 q-rows. K tiles double-buffered in LDS via
// global_load_lds (staged t+1 during tile t); V single-buffered, staged at tile
// top with S+softmax (~600 cyc) as cover before the pre-PV barrier drain.
// rel register-prefetched FIRST so its waitcnt leaves staging in flight.
// Barrier A (loop top) is drain-free; barrier B drains covered loads.
__global__ __launch_bounds__(256, 4) void attn_mfma(const unsigned short* __restrict__ qb,
    const unsigned short* __restrict__ kb, const unsigned short* __restrict__ vt,
    const void* __restrict__ rel, const int* __restrict__ flag,
    unsigned short* __restrict__ ob){
  // K: chunk-major [buf][chunk 0..5][row 0..63][8 shorts] (chunk = 16B of head-dim)
  // V: chunk-major [chunk 0..7][d 0..47][8 shorts]        (chunk = 16B of kv-cols)
  __shared__ __align__(16) unsigned short Kbuf[2][6*512];
  __shared__ __align__(16) unsigned short Vbuf[8*384];
  __shared__ __align__(16) unsigned short Ps[4][32][72];   // stride 144 B (16B-aligned); col 64 = lsum
  const int x = blockIdx.x;
  const int b = x >> 5, nb = x & 31, h = blockIdx.y;
  const int tid = threadIdx.x, wave = tid >> 6, lane = tid & 63;
  const int lg = lane >> 4, ln = lane & 15;
  const int qrow0 = nb * 128 + wave * 32;
  const bool bfm = (*flag != 0);
  const float SCL = 0.14433756729740643f * LOG2E;

  // Q fragments (B-operand; pad 48->64 with 0)
  bf16x8 qf0[2], qf1[2];
  #pragma unroll
  for (int qt = 0; qt < 2; ++qt) {
    const unsigned short* qp = qb + ((size_t)(b*4096 + qrow0 + qt*16 + ln))*384 + h*48;
    qf0[qt] = *(const bf16x8*)(qp + lg*8);
    bf16x8 z = {0,0,0,0,0,0,0,0};
    if (lg < 2) z = *(const bf16x8*)(qp + 32 + lg*8);
    qf1[qt] = z;
  }

  f32x4 o[2][3];
  #pragma unroll
  for (int qt = 0; qt < 2; ++qt) { o[qt][0] = (f32x4){0.f,0.f,0.f,0.f}; o[qt][1] = o[qt][0]; o[qt][2] = o[qt][0]; }
  float lsum[2] = {0.f, 0.f};

  const float* relf = (const float*)rel;
  const unsigned short* relh = (const unsigned short*)rel;
  const size_t rbase = ((size_t)(h*4096 + qrow0 + ln)) * 1024;
  const size_t kbase = (size_t)(b*1024) * 384 + (size_t)h*48;   // shorts
  const size_t vbase = ((size_t)(b*8 + h)) * 48 * 1024;          // shorts

  // staging assignments: 6 K-insts + 6 V-insts split 3/wave
  const int jk1 = wave;
  const int jk2 = 4 + wave;              // valid for wave<2
  const int jv1 = wave;
  const int jv2 = 2 + wave;              // valid for wave>=2
  // V lane->(c,d) mapping per assigned inst (loop-invariant)
  int s1 = jv1*64 + lane;  int c1 = s1/48, d1 = s1 - 48*c1;
  size_t vg1 = vbase + (size_t)d1*1024 + c1*8;
  int s2 = jv2*64 + lane;  int c2 = s2/48, d2 = s2 - 48*c2;
  size_t vg2 = vbase + (size_t)d2*1024 + c2*8;

  // prologue: stage K(0) into buf 0
  gld_lds16(kb + kbase + (size_t)lane*384 + jk1*8, &Kbuf[0][jk1*512]);
  if (wave < 2) gld_lds16(kb + kbase + (size_t)lane*384 + jk2*8, &Kbuf[0][jk2*512]);

  #pragma unroll 1
  for (int t = 0; t < 16; ++t) {
    const int cbuf = t & 1, nbuf = cbuf ^ 1;
    __syncthreads();     // A: drain-free (nothing in flight); protects Vbuf/Kbuf[nbuf]

    // rel prefetch FIRST (oldest in vmcnt queue)
    uint2 rr[2][4];
    if (bfm) {
      #pragma unroll
      for (int qt = 0; qt < 2; ++qt)
        #pragma unroll
        for (int mt = 0; mt < 4; ++mt)
          rr[qt][mt] = *(const uint2*)(relh + rbase + (size_t)qt*16384 + t*64 + mt*16 + lg*4);
    } else {
      #pragma unroll
      for (int qt = 0; qt < 2; ++qt)
        #pragma unroll
        for (int mt = 0; mt < 4; ++mt) {
          float4 q_ = *(const float4*)(relf + rbase + (size_t)qt*16384 + t*64 + mt*16 + lg*4);
          rr[qt][mt].x = pk2bf(q_.x, q_.y); rr[qt][mt].y = pk2bf(q_.z, q_.w);
        }
    }

    // async staging: V(t) and K(t+1)
    gld_lds16(vt + vg1 + t*64, &Vbuf[jv1*512]);
    if (wave >= 2) gld_lds16(vt + vg2 + t*64, &Vbuf[jv2*512]);
    const int T = (t + 1 < 16) ? t + 1 : 15;
    gld_lds16(kb + kbase + (size_t)T*24576 + (size_t)lane*384 + jk1*8, &Kbuf[nbuf][jk1*512]);
    if (wave < 2) gld_lds16(kb + kbase + (size_t)T*24576 + (size_t)lane*384 + jk2*8, &Kbuf[nbuf][jk2*512]);

    // S-phase: K frags from LDS (staged last tile), 16 MFMAs
    f32x4 s[4][2];
    #pragma unroll
    for (int mt = 0; mt < 4; ++mt) {
      bf16x8 k0 = *(const bf16x8*)&Kbuf[cbuf][lg*512 + (mt*16 + ln)*8];
      bf16x8 k1 = {0,0,0,0,0,0,0,0};
      if (lg < 2) k1 = *(const bf16x8*)&Kbuf[cbuf][(4 + lg)*512 + (mt*16 + ln)*8];
      #pragma unroll
      for (int qt = 0; qt < 2; ++qt) {
        s[mt][qt] = __builtin_amdgcn_mfma_f32_16x16x32_bf16(k0, qf0[qt], (f32x4){0.f,0.f,0.f,0.f}, 0, 0, 0);
        s[mt][qt] = __builtin_amdgcn_mfma_f32_16x16x32_bf16(k1, qf1[qt], s[mt][qt], 0, 0, 0);
      }
    }

    // softmax numerator (no-max: scores O(1)); P -> wave-private Ps rows
    #pragma unroll
    for (int qt = 0; qt < 2; ++qt) {
      float lacc = 0.f;
      #pragma unroll
      for (int mt = 0; mt < 4; ++mt) {
        float r0 = bf_lo(rr[qt][mt].x), r1 = bf_hi(rr[qt][mt].x);
        float r2 = bf_lo(rr[qt][mt].y), r3 = bf_hi(rr[qt][mt].y);
        float p0 = exp2f(fmaf(s[mt][qt][0], SCL, r0 * LOG2E));
        float p1 = exp2f(fmaf(s[mt][qt][1], SCL, r1 * LOG2E));
        float p2 = exp2f(fmaf(s[mt][qt][2], SCL, r2 * LOG2E));
        float p3 = exp2f(fmaf(s[mt][qt][3], SCL, r3 * LOG2E));
        lacc += (p0 + p1) + (p2 + p3);
        uint2 w; w.x = pkcvt(p0, p1); w.y = pkcvt(p2, p3);
        *(uint2*)&Ps[wave][qt*16 + ln][mt*16 + lg*4] = w;
      }
      lsum[qt] += lacc;
    }

    __syncthreads();     // B: vmcnt(0) drain -> V(t)/K(t+1) in LDS (issued ~600 cyc ago)

    // PV-phase: V frags + P frags from LDS, 12 MFMAs
    #pragma unroll
    for (int ks = 0; ks < 2; ++ks) {
      bf16x8 vf[3];
      #pragma unroll
      for (int nd = 0; nd < 3; ++nd)
        vf[nd] = *(const bf16x8*)&Vbuf[(ks*4 + lg)*384 + (nd*16 + ln)*8];
      #pragma unroll
      for (int qt = 0; qt < 2; ++qt) {
        bf16x8 pa = *(const bf16x8*)&Ps[wave][qt*16 + ln][ks*32 + lg*8];
        #pragma unroll
        for (int nd = 0; nd < 3; ++nd)
          o[qt][nd] = __builtin_amdgcn_mfma_f32_16x16x32_bf16(pa, vf[nd], o[qt][nd], 0, 0, 0);
      }
    }
  }

  // l: reduce across the 4 lg-lanes of each q-row; transpose via Ps pad col 64
  #pragma unroll
  for (int qt = 0; qt < 2; ++qt) {
    lsum[qt] += __shfl_xor(lsum[qt], 16, 64);
    lsum[qt] += __shfl_xor(lsum[qt], 32, 64);
    if (lg == 0) *(float*)&Ps[wave][qt*16 + ln][64] = lsum[qt];
  }
  #pragma unroll
  for (int qt = 0; qt < 2; ++qt)
    #pragma unroll
    for (int r = 0; r < 4; ++r) {
      float l = *(const float*)&Ps[wave][qt*16 + lg*4 + r][64];
      float linv = 1.0f / l;
      size_t rowb = ((size_t)(b*4096 + qrow0 + qt*16 + lg*4 + r))*384 + h*48 + ln;
      #pragma unroll
      for (int nd = 0; nd < 3; ++nd)
        ob[rowb + nd*16] = f2bf(o[qt][nd][r] * linv);
    }
}

extern "C" void kernel_launch(void* const* d_in, const int* in_sizes, int n_in,
                              void* d_out, int out_size, void* d_ws, size_t ws_size,
                              hipStream_t stream) {
  // d_in: 0=x 1=relative_pos 2=H 3=W 4=Wq 5=Wk 6=Wv 7=Wp 8=bp 9=sr_w 10=sr_b
  //       11=bn_gamma 12=bn_beta 13=bn_mean 14=bn_var
  float* ws = (float*)d_ws;
  int* flag = (int*)d_ws;
  unsigned short* u = (unsigned short*)d_ws;

  detect_bf16<<<1, 64, 0, stream>>>((const unsigned*)d_in[0], flag);
  convert_all<<<3363, 256, 0, stream>>>(d_in[0], d_in[4], d_in[5], d_in[6], d_in[7],
      d_in[8], d_in[9], d_in[10], d_in[11], d_in[12], d_in[13], d_in[14], ws);
  sr_bn<<<768, 256, 0, stream>>>(u + U_XB, ws, u + U_XK);
  proj_qkv<<<dim3(3, 192), 256, 0, stream>>>(u);
  attn_mfma<<<dim3(128, 8), 256, 0, stream>>>(u + U_QB, u + U_KB, u + U_VT, d_in[1], flag, u + U_OB);
  gemm_out<<<dim3(3, 128), 256, 0, stream>>>(u + U_OB, u + U_WP, ws + OFF_BPf, d_out, flag);
}